// Round 1
// 2602.847 us; speedup vs baseline: 1.6932x; 1.6932x over previous
//
#include <hip/hip_runtime.h>
#include <math.h>

#define HID 4096
#define NMAX 2048
#define EMAX 16384
#define RREL 4
#define NTOT 4096  // 1024 (pre) + 1024 (hyp) + 2048 (comb), node-batched

typedef unsigned short ushortT;
typedef __attribute__((ext_vector_type(8))) short short8;
typedef __attribute__((ext_vector_type(4))) float floatx4;

// async global->LDS, 16B per lane (dest = wave-uniform base + lane*16)
#define GLDS(gp, lp)                                                                        \
  __builtin_amdgcn_global_load_lds((const __attribute__((address_space(1))) unsigned*)(gp), \
                                   (__attribute__((address_space(3))) unsigned*)(lp), 16, 0, 0)

// ---------- helpers ----------
__device__ __forceinline__ ushortT f2b(float f) {  // fp32 -> bf16 RNE
  unsigned u = __float_as_uint(f);
  u = u + 0x7fffu + ((u >> 16) & 1u);
  return (ushortT)(u >> 16);
}
__device__ __forceinline__ float b2f_lo(unsigned u) { return __uint_as_float(u << 16); }
__device__ __forceinline__ float b2f_hi(unsigned u) { return __uint_as_float(u & 0xffff0000u); }
__device__ __forceinline__ float b2f1(ushortT u) { return __uint_as_float((unsigned)u << 16); }

// ---------- weight convert + transpose: W[K][4096] fp32 -> Wt[4096][K] bf16 ----------
__global__ __launch_bounds__(256) void convt_k(const float* __restrict__ W,
                                               ushortT* __restrict__ Wt, int K) {
  int bn = blockIdx.x * 32;  // column (n) tile of W
  int bk = blockIdx.y * 32;  // row (k) tile of W
  int t = threadIdx.x;
  __shared__ ushortT tile[32][40];  // [n][k]
  int kr = t >> 3;
  int nc = (t & 7) * 4;
  float4 v = *(const float4*)(W + (size_t)(bk + kr) * 4096 + bn + nc);
  tile[nc + 0][kr] = f2b(v.x);
  tile[nc + 1][kr] = f2b(v.y);
  tile[nc + 2][kr] = f2b(v.z);
  tile[nc + 3][kr] = f2b(v.w);
  __syncthreads();
  int n = t >> 3, j = (t & 7) * 4;
  uint2 u;
  u.x = (unsigned)tile[n][j] | ((unsigned)tile[n][j + 1] << 16);
  u.y = (unsigned)tile[n][j + 2] | ((unsigned)tile[n][j + 3] << 16);
  *(uint2*)(Wt + (size_t)(bn + n) * K + bk + j) = u;
}

// ---------- sum 4 relation residual mats then convert+transpose (K=1024) ----------
__global__ __launch_bounds__(256) void convtsum_k(const float* __restrict__ W,
                                                  ushortT* __restrict__ Wt, int K) {
  int bn = blockIdx.x * 32;
  int bk = blockIdx.y * 32;
  int t = threadIdx.x;
  __shared__ ushortT tile[32][40];
  int kr = t >> 3;
  int nc = (t & 7) * 4;
  const size_t S = (size_t)1024 * HID;
  size_t base = (size_t)(bk + kr) * 4096 + bn + nc;
  float4 v0 = *(const float4*)(W + base);
  float4 v1 = *(const float4*)(W + base + S);
  float4 v2 = *(const float4*)(W + base + 2 * S);
  float4 v3 = *(const float4*)(W + base + 3 * S);
  tile[nc + 0][kr] = f2b(v0.x + v1.x + v2.x + v3.x);
  tile[nc + 1][kr] = f2b(v0.y + v1.y + v2.y + v3.y);
  tile[nc + 2][kr] = f2b(v0.z + v1.z + v2.z + v3.z);
  tile[nc + 3][kr] = f2b(v0.w + v1.w + v2.w + v3.w);
  __syncthreads();
  int n = t >> 3, j = (t & 7) * 4;
  uint2 u;
  u.x = (unsigned)tile[n][j] | ((unsigned)tile[n][j + 1] << 16);
  u.y = (unsigned)tile[n][j + 2] | ((unsigned)tile[n][j + 3] << 16);
  *(uint2*)(Wt + (size_t)(bn + n) * K + bk + j) = u;
}

// ---------- plain fp32 -> bf16 convert ----------
__global__ void f2b_k(const float* __restrict__ in, ushortT* __restrict__ out, int n8) {
  int i = blockIdx.x * 256 + threadIdx.x;
  if (i >= n8) return;
  const float4* p = (const float4*)in;
  float4 a = p[2 * i], b = p[2 * i + 1];
  uint4 u;
  u.x = (unsigned)f2b(a.x) | ((unsigned)f2b(a.y) << 16);
  u.y = (unsigned)f2b(a.z) | ((unsigned)f2b(a.w) << 16);
  u.z = (unsigned)f2b(b.x) | ((unsigned)f2b(b.y) << 16);
  u.w = (unsigned)f2b(b.z) | ((unsigned)f2b(b.w) << 16);
  *(uint4*)(out + 8 * i) = u;
}

// ---------- bf16 MFMA GEMM (m97 structure): C[M,4096] = A[M,K] @ Bt[4096,K]^T ----------
// mode 0: C = (fp32)    mode 2: Cb = (bf16)
__global__ __launch_bounds__(256) void gemm_bt(const ushortT* __restrict__ A,
                                               const ushortT* __restrict__ Bt,
                                               float* __restrict__ C,
                                               ushortT* __restrict__ Cb,
                                               int M, int K, int mode) {
  __shared__ ushortT As[128 * 32];  // linear [row][k], BK=32
  __shared__ ushortT Bs[128 * 32];
  int t = threadIdx.x;
  int row0 = blockIdx.y * 128, col0 = blockIdx.x * 128;
  int sr = t >> 2;         // 0..63 staging row
  int sk = (t & 3) * 8;    // k-offset of 16B chunk
  const ushortT* Ap0 = A + (size_t)(row0 + sr) * K + sk;
  const ushortT* Ap1 = Ap0 + (size_t)64 * K;
  const ushortT* Bp0 = Bt + (size_t)(col0 + sr) * K + sk;
  const ushortT* Bp1 = Bp0 + (size_t)64 * K;
  // LDS dest: t*8 elems == (t>>2)*32 + (t&3)*8, lane-linear from each wave base
  ushortT* As0 = As + t * 8;
  ushortT* As1 = As + 2048 + t * 8;
  ushortT* Bs0 = Bs + t * 8;
  ushortT* Bs1 = Bs + 2048 + t * 8;
  int wave = t >> 6, lane = t & 63;
  int wr = (wave & 1) * 64, wc = (wave >> 1) * 64;
  int lrow = lane & 15, lkg = lane >> 4;
  floatx4 acc[4][4];
#pragma unroll
  for (int r = 0; r < 4; r++)
#pragma unroll
    for (int c = 0; c < 4; c++) acc[r][c] = (floatx4){0.f, 0.f, 0.f, 0.f};

  for (int kb = 0; kb < K; kb += 32) {
    GLDS(Ap0 + kb, As0);
    GLDS(Ap1 + kb, As1);
    GLDS(Bp0 + kb, Bs0);
    GLDS(Bp1 + kb, Bs1);
    __syncthreads();  // compiler drains vmcnt before barrier
    short8 af[4], bf[4];
#pragma unroll
    for (int r = 0; r < 4; r++)
      af[r] = *(const short8*)&As[(wr + r * 16 + lrow) * 32 + lkg * 8];
#pragma unroll
    for (int c = 0; c < 4; c++)
      bf[c] = *(const short8*)&Bs[(wc + c * 16 + lrow) * 32 + lkg * 8];
#pragma unroll
    for (int r = 0; r < 4; r++)
#pragma unroll
      for (int c = 0; c < 4; c++)
        acc[r][c] = __builtin_amdgcn_mfma_f32_16x16x32_bf16(af[r], bf[c], acc[r][c], 0, 0, 0);
    __syncthreads();
  }
  // epilogue: C/D layout col=lane&15, row=(lane>>4)*4+reg
#pragma unroll
  for (int r = 0; r < 4; r++) {
    int row = row0 + wr + r * 16 + lkg * 4;
#pragma unroll
    for (int c = 0; c < 4; c++) {
      int col = col0 + wc + c * 16 + lrow;
#pragma unroll
      for (int j = 0; j < 4; j++) {
        size_t idx = (size_t)(row + j) * HID + col;
        if (mode == 0) C[idx] = acc[r][c][j];
        else Cb[idx] = f2b(acc[r][c][j]);
      }
    }
  }
}

// ---------- el/er from bf16 feat (grid = NTOT rows) ----------
__global__ __launch_bounds__(256) void el_er_k(const ushortT* __restrict__ featb,
                                               const float* __restrict__ al,
                                               const float* __restrict__ ar,
                                               float* __restrict__ el,
                                               float* __restrict__ er) {
  int n = blockIdx.x, t = threadIdx.x;
  const unsigned* row = (const unsigned*)(featb + (size_t)n * HID);
  float pel[4] = {}, per_[4] = {};
#pragma unroll
  for (int j = 0; j < 8; j++) {
    unsigned u = row[j * 256 + t];
    int col = (j * 256 + t) * 2;
    const int h = j >> 1;
    pel[h] += b2f_lo(u) * al[col] + b2f_hi(u) * al[col + 1];
    per_[h] += b2f_lo(u) * ar[col] + b2f_hi(u) * ar[col + 1];
  }
  __shared__ float red[256][9];
#pragma unroll
  for (int h = 0; h < 4; h++) { red[t][h] = pel[h]; red[t][4 + h] = per_[h]; }
  __syncthreads();
  for (int s = 128; s > 0; s >>= 1) {
    if (t < s)
#pragma unroll
      for (int j = 0; j < 8; j++) red[t][j] += red[t + s][j];
    __syncthreads();
  }
  if (t < 4) { el[n * 4 + t] = red[0][t]; er[n * 4 + t] = red[0][4 + t]; }
}

// ---------- CSR build (batched over relations via blockIdx.y) ----------
__global__ void count_k(const int* __restrict__ dst, int* __restrict__ counts, int E) {
  int r = blockIdx.y;
  int i = blockIdx.x * blockDim.x + threadIdx.x;
  if (i < E) atomicAdd(&counts[r * NMAX + dst[(size_t)r * E + i]], 1);
}

__global__ __launch_bounds__(256) void scan_k(const int* __restrict__ counts,
                                              int* __restrict__ row_ptr, int N) {
  const int* cnt = counts + blockIdx.x * NMAX;
  int* rp = row_ptr + blockIdx.x * (NMAX + 1);
  __shared__ int sums[256];
  int t = threadIdx.x;
  int per = (N + 255) / 256;
  int local[8];
  int base = t * per;
  int s = 0;
  for (int i = 0; i < per; i++) {
    int idx = base + i;
    int v = (idx < N) ? cnt[idx] : 0;
    s += v;
    local[i] = s;
  }
  sums[t] = s;
  __syncthreads();
  for (int off = 1; off < 256; off <<= 1) {
    int v = (t >= off) ? sums[t - off] : 0;
    __syncthreads();
    sums[t] += v;
    __syncthreads();
  }
  int offset = (t > 0) ? sums[t - 1] : 0;
  for (int i = 0; i < per; i++) {
    int idx = base + i;
    if (idx < N) rp[idx + 1] = offset + local[i];
  }
  if (t == 0) rp[0] = 0;
}

__global__ void scatter_k(const int* __restrict__ dst, int* __restrict__ cnt,
                          const int* __restrict__ row_ptr, int* __restrict__ edge_ord,
                          int E) {
  int r = blockIdx.y;
  int i = blockIdx.x * blockDim.x + threadIdx.x;
  if (i < E) {
    int d = dst[(size_t)r * E + i];
    int off = atomicAdd(&cnt[r * NMAX + d], 1);
    edge_ord[(size_t)r * EMAX + row_ptr[r * (NMAX + 1) + d] + off] = i;
  }
}

// ---------- fused edge softmax: per (gnode, head), CSR walk, no atomics ----------
// stores unnormalized p and rinv = 1/sum (normalization folded into agg)
__global__ void sm_k(const int* __restrict__ sp0, const int* __restrict__ sp1,
                     const int* __restrict__ sp2,
                     const int* __restrict__ row_ptr, const int* __restrict__ edge_ord,
                     const float* __restrict__ el, const float* __restrict__ er,
                     float* __restrict__ p, float* __restrict__ rinv, int r) {
  int i = blockIdx.x * 256 + threadIdx.x;  // 0 .. NTOT*4-1
  int gnode = i >> 2, h = i & 3;
  int g = (gnode < 2048) ? (gnode >> 10) : 2;
  int goff = (g == 2) ? 2048 : (g << 10);
  int n = gnode - goff;
  const int* rp = row_ptr + (g * RREL + r) * (NMAX + 1);
  int start = rp[n], end = rp[n + 1];
  float rv = 0.f;
  if (end > start) {
    const int* eo = edge_ord + ((size_t)g * RREL + r) * EMAX;
    const int* srcg = (g == 0) ? sp0 : (g == 1) ? sp1 : sp2;
    float erv = er[gnode * 4 + h];
    float m = -3.4e38f;
    for (int c = start; c < end; c++) {
      float v = el[(goff + srcg[eo[c]]) * 4 + h] + erv;
      v = v > 0.f ? v : 0.2f * v;
      m = fmaxf(m, v);
    }
    float s = 0.f;
    float* pg = p + (size_t)g * EMAX * 4;
    for (int c = start; c < end; c++) {
      int eid = eo[c];
      float v = el[(goff + srcg[eid]) * 4 + h] + erv;
      v = v > 0.f ? v : 0.2f * v;
      float pv = expf(v - m);
      pg[eid * 4 + h] = pv;
      s += pv;
    }
    rv = 1.f / s;  // s >= 1 (max edge contributes exp(0))
  }
  rinv[gnode * 4 + h] = rv;
}

// ---------- aggregation (grid = NTOT nodes, all graphs; one relation per launch) ----------
__global__ __launch_bounds__(256) void agg_k(const ushortT* __restrict__ featb,
                                             const float* __restrict__ p,
                                             const float* __restrict__ rinv,
                                             const int* __restrict__ row_ptr,
                                             const int* __restrict__ edge_ord,
                                             const int* __restrict__ sp0,
                                             const int* __restrict__ sp1,
                                             const int* __restrict__ sp2,
                                             float* __restrict__ acc, int r) {
  int gnode = blockIdx.x;
  int g = (gnode < 2048) ? (gnode >> 10) : 2;
  int goff = (g == 2) ? 2048 : (g << 10);
  int n = gnode - goff;
  const int* rp = row_ptr + (g * RREL + r) * (NMAX + 1);
  int start = rp[n], end = rp[n + 1];
  if (end == start) return;
  const int* eo = edge_ord + ((size_t)g * RREL + r) * EMAX;
  const int* srcg = (g == 0) ? sp0 : (g == 1) ? sp1 : sp2;
  const float* pg = p + (size_t)g * EMAX * 4;
  __shared__ int s_src[256];
  __shared__ float s_al[256][4];
  int t = threadIdx.x;
  float o0[8] = {}, o1[8] = {};
  for (int c = start; c < end; c += 256) {
    int m = min(256, end - c);
    if (t < m) {
      int eid = eo[c + t];
      s_src[t] = srcg[eid];
#pragma unroll
      for (int h = 0; h < 4; h++) s_al[t][h] = pg[eid * 4 + h];
    }
    __syncthreads();
    for (int i = 0; i < m; i++) {
      const unsigned* frow = (const unsigned*)(featb + (size_t)(goff + s_src[i]) * HID);
      float a0 = s_al[i][0], a1 = s_al[i][1], a2 = s_al[i][2], a3 = s_al[i][3];
#pragma unroll
      for (int j = 0; j < 8; j++) {
        unsigned u = frow[j * 256 + t];
        float av = (j < 2) ? a0 : (j < 4) ? a1 : (j < 6) ? a2 : a3;
        o0[j] += av * b2f_lo(u);
        o1[j] += av * b2f_hi(u);
      }
    }
    __syncthreads();
  }
  float rv[4];
#pragma unroll
  for (int h = 0; h < 4; h++) rv[h] = rinv[gnode * 4 + h];
#pragma unroll
  for (int j = 0; j < 8; j++) {
    float sc = rv[j >> 1];
    float2* pa = (float2*)(acc + (size_t)gnode * HID + (size_t)(j * 256 + t) * 2);
    float2 v = *pa;
    v.x += o0[j] * sc;
    v.y += o1[j] * sc;
    *pa = v;
  }
}

// ---------- finalize layer1: hb = bf16(elu((acc + sum_r b1)/4)) ----------
__global__ __launch_bounds__(256) void finalize1_k(const float* __restrict__ acc,
                                                   const float* __restrict__ b1,
                                                   ushortT* __restrict__ hb, int total) {
  int i = blockIdx.x * 256 + threadIdx.x;
  if (i >= total) return;
  int col = i & (HID - 1);
  float bs = b1[col] + b1[HID + col] + b1[2 * HID + col] + b1[3 * HID + col];
  float v = (acc[i] + bs) * 0.25f;
  v = v > 0.f ? v : (expf(v) - 1.f);
  hb[i] = f2b(v);
}

// ---------- finalize layer2 + column mean ----------
__global__ __launch_bounds__(256) void finalize2_mean_k(const float* __restrict__ acc,
                                                        const ushortT* __restrict__ hb,
                                                        const float* __restrict__ b2,
                                                        float* __restrict__ gm, int Nn,
                                                        float invN) {
  int col = blockIdx.x * 256 + threadIdx.x;
  int r0 = blockIdx.y * 32;
  int r1 = min(r0 + 32, Nn);
  float bs = 0.25f * (b2[col] + b2[HID + col] + b2[2 * HID + col] + b2[3 * HID + col]);
  float p = 0.f;
  for (int r = r0; r < r1; r++) {
    size_t i = (size_t)r * HID + col;
    p += acc[i] * 0.25f + b2f1(hb[i]) + bs;
  }
  atomicAdd(&gm[col], p * invN);
}

// ---------- readout MLP ----------
__global__ void initvec_k(float* __restrict__ out, const float* __restrict__ b, int n) {
  int i = blockIdx.x * blockDim.x + threadIdx.x;
  if (i < n) out[i] = b[i];
}

__global__ __launch_bounds__(256) void matvec_k(const float* __restrict__ v,
                                                const float* __restrict__ W,
                                                float* __restrict__ out, int K, int Nout,
                                                int kchunk) {
  int j = blockIdx.x * 256 + threadIdx.x;
  if (j >= Nout) return;
  int k0 = blockIdx.y * kchunk;
  int k1 = min(k0 + kchunk, K);
  float p = 0.f;
  for (int k = k0; k < k1; k++) p += v[k] * W[(size_t)k * Nout + j];
  atomicAdd(&out[j], p);
}

__global__ __launch_bounds__(256) void final_k(const float* __restrict__ hc,
                                               const float* __restrict__ Wc2,
                                               const float* __restrict__ bc2,
                                               float* __restrict__ out) {
  __shared__ float red[256];
  int t = threadIdx.x;
  for (int c = 0; c < 3; c++) {
    float p = 0.f;
    for (int k = t; k < 1024; k += 256) {
      float v = hc[k];
      v = v > 0.f ? v : 0.f;
      p += v * Wc2[k * 3 + c];
    }
    red[t] = p;
    __syncthreads();
    for (int s = 128; s > 0; s >>= 1) {
      if (t < s) red[t] += red[t + s];
      __syncthreads();
    }
    if (t == 0) out[c] = red[0] + bc2[c];
    __syncthreads();
  }
}

// ================= host side =================
extern "C" void kernel_launch(void* const* d_in, const int* in_sizes, int n_in,
                              void* d_out, int out_size, void* d_ws, size_t ws_size,
                              hipStream_t stream) {
  const float* x_pre = (const float*)d_in[0];
  const float* x_hyp = (const float*)d_in[1];
  const float* x_comb = (const float*)d_in[2];
  const int* src_pre = (const int*)d_in[3];
  const int* dst_pre = (const int*)d_in[4];
  const int* src_hyp = (const int*)d_in[5];
  const int* dst_hyp = (const int*)d_in[6];
  const int* src_comb = (const int*)d_in[7];
  const int* dst_comb = (const int*)d_in[8];
  const float* W1 = (const float*)d_in[9];
  const float* al1 = (const float*)d_in[10];
  const float* ar1 = (const float*)d_in[11];
  const float* b1 = (const float*)d_in[12];
  const float* res1 = (const float*)d_in[13];
  const float* W2 = (const float*)d_in[14];
  const float* al2 = (const float*)d_in[15];
  const float* ar2 = (const float*)d_in[16];
  const float* b2 = (const float*)d_in[17];
  const float* Wp = (const float*)d_in[18];
  const float* bp = (const float*)d_in[19];
  const float* Wc1 = (const float*)d_in[20];
  const float* bc1 = (const float*)d_in[21];
  const float* Wc2 = (const float*)d_in[22];
  const float* bc2 = (const float*)d_in[23];
  float* out = (float*)d_out;

  char* w = (char*)d_ws;
  size_t off = 0;
  auto alloc = [&](size_t bytes) -> void* {
    void* p = w + off;
    off = (off + bytes + 255) & ~(size_t)255;
    return p;
  };
  float* acc = (float*)alloc((size_t)NTOT * HID * 4);        // 64 MB, node-batched
  ushortT* hb = (ushortT*)alloc((size_t)NTOT * HID * 2);     // 32 MB
  ushortT* featb = (ushortT*)alloc((size_t)NTOT * HID * 2);  // 32 MB
  ushortT* xb = (ushortT*)alloc((size_t)NTOT * 1024 * 2);    // 8 MB
  ushortT* Wt = (ushortT*)alloc((size_t)HID * HID * 2);      // 32 MB
  float* el = (float*)alloc(NTOT * 4 * 4);
  float* er = (float*)alloc(NTOT * 4 * 4);
  float* pbuf = (float*)alloc((size_t)3 * EMAX * 4 * 4);
  float* rinv = (float*)alloc(NTOT * 4 * 4);
  int* row_ptr = (int*)alloc(3 * RREL * (NMAX + 1) * 4);
  int* edge_ord = (int*)alloc((size_t)3 * RREL * EMAX * 4);
  int* counts = (int*)alloc(RREL * NMAX * 4);
  float* gm = (float*)alloc(3 * HID * 4);
  float* z = (float*)alloc(3072 * 4);
  float* hc = (float*)alloc(1024 * 4);

  hipMemsetAsync(gm, 0, 3 * HID * 4, stream);

  struct GDesc { const float* x; const int* src; const int* dst; int N; int E; int goff; };
  GDesc gs[3] = {{x_pre, src_pre, dst_pre, 1024, 8192, 0},
                 {x_hyp, src_hyp, dst_hyp, 1024, 8192, 1024},
                 {x_comb, src_comb, dst_comb, 2048, 16384, 2048}};

  // CSR per (graph, relation) — built once, used by both layers
  for (int g = 0; g < 3; g++) {
    int N = gs[g].N, E = gs[g].E;
    int eb = E / 256;
    int* rpG = row_ptr + g * RREL * (NMAX + 1);
    int* eoG = edge_ord + (size_t)g * RREL * EMAX;
    hipMemsetAsync(counts, 0, RREL * NMAX * 4, stream);
    count_k<<<dim3(eb, RREL), 256, 0, stream>>>(gs[g].dst, counts, E);
    scan_k<<<RREL, 256, 0, stream>>>(counts, rpG, N);
    hipMemsetAsync(counts, 0, RREL * NMAX * 4, stream);
    scatter_k<<<dim3(eb, RREL), 256, 0, stream>>>(gs[g].dst, counts, rpG, eoG, E);
  }

  // x -> bf16, node-batched layout
  for (int g = 0; g < 3; g++)
    f2b_k<<<gs[g].N * 1024 / 8 / 256, 256, 0, stream>>>(gs[g].x,
                                                        xb + (size_t)gs[g].goff * 1024,
                                                        gs[g].N * 1024 / 8);

  dim3 gemmGrid(HID / 128, NTOT / 128);  // 32 x 32 = 1024 blocks

  for (int layer = 0; layer < 2; layer++) {
    int K = (layer == 0) ? 1024 : HID;
    const ushortT* Ab = (layer == 0) ? xb : hb;
    const float* Wl = (layer == 0) ? W1 : W2;
    const float* all = (layer == 0) ? al1 : al2;
    const float* arl = (layer == 0) ? ar1 : ar2;
    dim3 convGrid(HID / 32, K / 32);

    if (layer == 0) {
      // acc = x @ (sum_r res1_r): residual sum folded into ONE GEMM, inits acc (no memset)
      convtsum_k<<<convGrid, 256, 0, stream>>>(res1, Wt, 1024);
      gemm_bt<<<gemmGrid, 256, 0, stream>>>(xb, Wt, acc, (ushortT*)nullptr, NTOT, 1024, 0);
    } else {
      hipMemsetAsync(acc, 0, (size_t)NTOT * HID * 4, stream);
    }

    for (int r = 0; r < RREL; r++) {
      // weights converted once per (layer, relation) — shared by all 3 graphs
      convt_k<<<convGrid, 256, 0, stream>>>(Wl + (size_t)r * K * HID, Wt, K);
      gemm_bt<<<gemmGrid, 256, 0, stream>>>(Ab, Wt, (float*)nullptr, featb, NTOT, K, 2);
      el_er_k<<<NTOT, 256, 0, stream>>>(featb, all + r * HID, arl + r * HID, el, er);
      const int* sp0 = src_pre + (size_t)r * 8192;
      const int* sp1 = src_hyp + (size_t)r * 8192;
      const int* sp2 = src_comb + (size_t)r * 16384;
      sm_k<<<NTOT * 4 / 256, 256, 0, stream>>>(sp0, sp1, sp2, row_ptr, edge_ord, el, er,
                                               pbuf, rinv, r);
      agg_k<<<NTOT, 256, 0, stream>>>(featb, pbuf, rinv, row_ptr, edge_ord, sp0, sp1, sp2,
                                      acc, r);
    }

    if (layer == 0) {
      finalize1_k<<<(size_t)NTOT * HID / 256, 256, 0, stream>>>(acc, b1, hb, NTOT * HID);
    } else {
      for (int g = 0; g < 3; g++) {
        dim3 fg(HID / 256, (gs[g].N + 31) / 32);
        finalize2_mean_k<<<fg, 256, 0, stream>>>(acc + (size_t)gs[g].goff * HID,
                                                 hb + (size_t)gs[g].goff * HID, b2,
                                                 gm + g * HID, gs[g].N, 1.0f / gs[g].N);
      }
    }
  }

  // readout MLP (fp32)
  initvec_k<<<12, 256, 0, stream>>>(z, bp, 3072);
  {
    dim3 mg(3072 / 256, 48);
    matvec_k<<<mg, 256, 0, stream>>>(gm, Wp, z, 12288, 3072, 256);
  }
  initvec_k<<<4, 256, 0, stream>>>(hc, bc1, 1024);
  {
    dim3 mg(1024 / 256, 24);
    matvec_k<<<mg, 256, 0, stream>>>(z, Wc1, hc, 3072, 1024, 128);
  }
  final_k<<<1, 256, 0, stream>>>(hc, Wc2, bc2, out);
}

// Round 2
// 2181.895 us; speedup vs baseline: 2.0198x; 1.1929x over previous
//
#include <hip/hip_runtime.h>
#include <math.h>

#define HID 4096
#define NMAX 2048
#define EMAX 16384
#define RREL 4
#define NTOT 4096  // 1024 (pre) + 1024 (hyp) + 2048 (comb), node-batched

typedef unsigned short ushortT;
typedef __attribute__((ext_vector_type(8))) short short8;
typedef __attribute__((ext_vector_type(4))) float floatx4;

// async global->LDS, 16B per lane (dest = wave-uniform base + lane*16)
#define GLDS(gp, lp)                                                                        \
  __builtin_amdgcn_global_load_lds((const __attribute__((address_space(1))) unsigned*)(gp), \
                                   (__attribute__((address_space(3))) unsigned*)(lp), 16, 0, 0)

// ---------- helpers ----------
__device__ __forceinline__ ushortT f2b(float f) {  // fp32 -> bf16 RNE
  unsigned u = __float_as_uint(f);
  u = u + 0x7fffu + ((u >> 16) & 1u);
  return (ushortT)(u >> 16);
}
__device__ __forceinline__ float b2f_lo(unsigned u) { return __uint_as_float(u << 16); }
__device__ __forceinline__ float b2f_hi(unsigned u) { return __uint_as_float(u & 0xffff0000u); }
__device__ __forceinline__ float b2f1(ushortT u) { return __uint_as_float((unsigned)u << 16); }

// ---------- weight convert + transpose: W[K][4096] fp32 -> Wt[4096][K] bf16 ----------
__global__ __launch_bounds__(256) void convt_k(const float* __restrict__ W,
                                               ushortT* __restrict__ Wt, int K) {
  int bn = blockIdx.x * 32;  // column (n) tile of W
  int bk = blockIdx.y * 32;  // row (k) tile of W
  int t = threadIdx.x;
  __shared__ ushortT tile[32][40];  // [n][k]
  int kr = t >> 3;
  int nc = (t & 7) * 4;
  float4 v = *(const float4*)(W + (size_t)(bk + kr) * 4096 + bn + nc);
  tile[nc + 0][kr] = f2b(v.x);
  tile[nc + 1][kr] = f2b(v.y);
  tile[nc + 2][kr] = f2b(v.z);
  tile[nc + 3][kr] = f2b(v.w);
  __syncthreads();
  int n = t >> 3, j = (t & 7) * 4;
  uint2 u;
  u.x = (unsigned)tile[n][j] | ((unsigned)tile[n][j + 1] << 16);
  u.y = (unsigned)tile[n][j + 2] | ((unsigned)tile[n][j + 3] << 16);
  *(uint2*)(Wt + (size_t)(bn + n) * K + bk + j) = u;
}

// ---------- sum 4 relation residual mats then convert+transpose (K=1024) ----------
__global__ __launch_bounds__(256) void convtsum_k(const float* __restrict__ W,
                                                  ushortT* __restrict__ Wt, int K) {
  int bn = blockIdx.x * 32;
  int bk = blockIdx.y * 32;
  int t = threadIdx.x;
  __shared__ ushortT tile[32][40];
  int kr = t >> 3;
  int nc = (t & 7) * 4;
  const size_t S = (size_t)1024 * HID;
  size_t base = (size_t)(bk + kr) * 4096 + bn + nc;
  float4 v0 = *(const float4*)(W + base);
  float4 v1 = *(const float4*)(W + base + S);
  float4 v2 = *(const float4*)(W + base + 2 * S);
  float4 v3 = *(const float4*)(W + base + 3 * S);
  tile[nc + 0][kr] = f2b(v0.x + v1.x + v2.x + v3.x);
  tile[nc + 1][kr] = f2b(v0.y + v1.y + v2.y + v3.y);
  tile[nc + 2][kr] = f2b(v0.z + v1.z + v2.z + v3.z);
  tile[nc + 3][kr] = f2b(v0.w + v1.w + v2.w + v3.w);
  __syncthreads();
  int n = t >> 3, j = (t & 7) * 4;
  uint2 u;
  u.x = (unsigned)tile[n][j] | ((unsigned)tile[n][j + 1] << 16);
  u.y = (unsigned)tile[n][j + 2] | ((unsigned)tile[n][j + 3] << 16);
  *(uint2*)(Wt + (size_t)(bn + n) * K + bk + j) = u;
}

// ---------- plain fp32 -> bf16 convert ----------
__global__ void f2b_k(const float* __restrict__ in, ushortT* __restrict__ out, int n8) {
  int i = blockIdx.x * 256 + threadIdx.x;
  if (i >= n8) return;
  const float4* p = (const float4*)in;
  float4 a = p[2 * i], b = p[2 * i + 1];
  uint4 u;
  u.x = (unsigned)f2b(a.x) | ((unsigned)f2b(a.y) << 16);
  u.y = (unsigned)f2b(a.z) | ((unsigned)f2b(a.w) << 16);
  u.z = (unsigned)f2b(b.x) | ((unsigned)f2b(b.y) << 16);
  u.w = (unsigned)f2b(b.z) | ((unsigned)f2b(b.w) << 16);
  *(uint4*)(out + 8 * i) = u;
}

// ---------- 256x256-tile 4-phase bf16 MFMA GEMM, M=N=4096 fixed ----------
// 8 waves (2M x 4N), BK=32, double-buffered 64KB LDS, st_16x32 XOR swizzle,
// counted vmcnt (never 0 in steady state), raw s_barrier, setprio around MFMA.
// mode 0: C = (fp32)    mode 2: Cb = (bf16)
#define MIDB()                                         \
  __builtin_amdgcn_s_barrier();                        \
  asm volatile("s_waitcnt lgkmcnt(0)" ::: "memory");   \
  __builtin_amdgcn_sched_barrier(0);                   \
  __builtin_amdgcn_s_setprio(1)

#define RD_A(BASE, MH)                                                              \
  _Pragma("unroll") for (int f = 0; f < 4; f++)                                     \
      a[f] = *(const short8*)&lds[(BASE) + (wm * 128 + (MH)*64 + f * 16 + lrow) * 32 + kcol];
#define RD_B(BASE)                                                                  \
  _Pragma("unroll") for (int n = 0; n < 4; n++)                                     \
      b[n] = *(const short8*)&lds[(BASE) + 8192 + (wn * 64 + n * 16 + lrow) * 32 + kcol];
#define MFMA_H(MH)                                                                  \
  _Pragma("unroll") for (int f = 0; f < 4; f++)                                     \
  _Pragma("unroll") for (int n = 0; n < 4; n++)                                     \
      acc[(MH)*4 + f][n] =                                                          \
          __builtin_amdgcn_mfma_f32_16x16x32_bf16(a[f], b[n], acc[(MH)*4 + f][n], 0, 0, 0);
// stage half-tile H of K-tile KT into buffer BUF (one 16B load per thread)
#define SA(BUF, H, KT) GLDS(Asrc + (size_t)((H)*128) * K + (KT)*32, lds + (BUF)*16384 + (H)*4096 + t * 8)
#define SB(BUF, H, KT) GLDS(Bsrc + (size_t)((H)*128) * K + (KT)*32, lds + (BUF)*16384 + 8192 + (H)*4096 + t * 8)

__global__ __launch_bounds__(512, 1) void gemm256(const ushortT* __restrict__ A,
                                                  const ushortT* __restrict__ Bt,
                                                  float* __restrict__ C,
                                                  ushortT* __restrict__ Cb,
                                                  int K, int mode) {
  __shared__ ushortT lds[32768];  // [2 buf][A 8192 | B 8192] elems = 64 KB
  const int t = threadIdx.x;
  // XCD-aware swizzle: 256 blocks, 8 XCDs, 32 contiguous tiles per XCD
  int bid = blockIdx.x;
  int swz = (bid & 7) * 32 + (bid >> 3);
  const int row0 = (swz >> 4) * 256;
  const int col0 = (swz & 15) * 256;

  // staging source: linear LDS dest + inverse-swizzled global source (rule 21)
  const int rA = t >> 2;                                      // row 0..127 within half
  const int c8l = ((t & 3) ^ (((t >> 5) & 1) << 1)) * 8;      // swizzle-corrected col chunk
  const ushortT* Asrc = A + (size_t)(row0 + rA) * K + c8l;
  const ushortT* Bsrc = Bt + (size_t)(col0 + rA) * K + c8l;

  const int wave = t >> 6, lane = t & 63;
  const int wm = wave >> 2, wn = wave & 3;  // 2 x 4 wave grid
  const int lrow = lane & 15, lkg = lane >> 4;
  const int kcol = (lkg * 8) ^ (((lane >> 3) & 1) << 4);  // swizzled read col

  floatx4 acc[8][4];
#pragma unroll
  for (int f = 0; f < 8; f++)
#pragma unroll
    for (int n = 0; n < 4; n++) acc[f][n] = (floatx4){0.f, 0.f, 0.f, 0.f};
  short8 a[4], b[4];

  const int nT = K >> 5;   // K-tiles of 32
  const int nIt = nT >> 1; // 2 K-tiles per iteration

  // prologue: K0 full -> buf0; K1.B -> buf1
  SA(0, 0, 0); SA(0, 1, 0); SB(0, 0, 0); SB(0, 1, 0);
  SB(1, 0, 1); SB(1, 1, 1);
  asm volatile("s_waitcnt vmcnt(2)" ::: "memory");  // K0 landed; K1.B in flight
  __builtin_amdgcn_s_barrier();
  __builtin_amdgcn_sched_barrier(0);

#pragma unroll 1
  for (int it = 0; it < nIt; it++) {
    const int k1 = 2 * it + 1, k2 = 2 * it + 2, k3 = 2 * it + 3;
    const bool s2 = (k2 < nT), s3 = (k3 < nT);
    // ---- P1: buf0 mh0 ---- (stage K1.A -> buf1; buf1.A free since prev P4)
    RD_A(0, 0); RD_B(0);
    SA(1, 0, k1); SA(1, 1, k1);
    MIDB();
    MFMA_H(0);
    __builtin_amdgcn_s_setprio(0);
    __builtin_amdgcn_s_barrier();
    __builtin_amdgcn_sched_barrier(0);
    // ---- P2: buf0 mh1 ---- (stage K2.B -> buf0.B; read-complete at P1)
    RD_A(0, 1);
    if (s2) { SB(0, 0, k2); SB(0, 1, k2); }
    MIDB();
    MFMA_H(1);
    __builtin_amdgcn_s_setprio(0);
    if (s2) asm volatile("s_waitcnt vmcnt(2)" ::: "memory");  // K1 fully landed
    else    asm volatile("s_waitcnt vmcnt(0)" ::: "memory");
    __builtin_amdgcn_s_barrier();
    __builtin_amdgcn_sched_barrier(0);
    // ---- P3: buf1 mh0 ---- (stage K2.A -> buf0.A; read-complete at P2)
    RD_A(16384, 0); RD_B(16384);
    if (s2) { SA(0, 0, k2); SA(0, 1, k2); }
    MIDB();
    MFMA_H(0);
    __builtin_amdgcn_s_setprio(0);
    __builtin_amdgcn_s_barrier();
    __builtin_amdgcn_sched_barrier(0);
    // ---- P4: buf1 mh1 ---- (stage K3.B -> buf1.B; read-complete at P3)
    RD_A(16384, 1);
    if (s3) { SB(1, 0, k3); SB(1, 1, k3); }
    MIDB();
    MFMA_H(1);
    __builtin_amdgcn_s_setprio(0);
    if (s3) asm volatile("s_waitcnt vmcnt(2)" ::: "memory");  // K2 fully landed
    else    asm volatile("s_waitcnt vmcnt(0)" ::: "memory");
    __builtin_amdgcn_s_barrier();
    __builtin_amdgcn_sched_barrier(0);
  }

  // epilogue: C/D layout col=lane&15, row=(lane>>4)*4+reg
#pragma unroll
  for (int fr = 0; fr < 8; fr++) {
    int row = row0 + wm * 128 + fr * 16 + lkg * 4;
#pragma unroll
    for (int n = 0; n < 4; n++) {
      int col = col0 + wn * 64 + n * 16 + lrow;
#pragma unroll
      for (int j = 0; j < 4; j++) {
        size_t idx = (size_t)(row + j) * HID + col;
        if (mode == 0) C[idx] = acc[fr][n][j];
        else Cb[idx] = f2b(acc[fr][n][j]);
      }
    }
  }
}

// ---------- el/er from bf16 feat (grid = NTOT rows) ----------
__global__ __launch_bounds__(256) void el_er_k(const ushortT* __restrict__ featb,
                                               const float* __restrict__ al,
                                               const float* __restrict__ ar,
                                               float* __restrict__ el,
                                               float* __restrict__ er) {
  int n = blockIdx.x, t = threadIdx.x;
  const unsigned* row = (const unsigned*)(featb + (size_t)n * HID);
  float pel[4] = {}, per_[4] = {};
#pragma unroll
  for (int j = 0; j < 8; j++) {
    unsigned u = row[j * 256 + t];
    int col = (j * 256 + t) * 2;
    const int h = j >> 1;
    pel[h] += b2f_lo(u) * al[col] + b2f_hi(u) * al[col + 1];
    per_[h] += b2f_lo(u) * ar[col] + b2f_hi(u) * ar[col + 1];
  }
  __shared__ float red[256][9];
#pragma unroll
  for (int h = 0; h < 4; h++) { red[t][h] = pel[h]; red[t][4 + h] = per_[h]; }
  __syncthreads();
  for (int s = 128; s > 0; s >>= 1) {
    if (t < s)
#pragma unroll
      for (int j = 0; j < 8; j++) red[t][j] += red[t + s][j];
    __syncthreads();
  }
  if (t < 4) { el[n * 4 + t] = red[0][t]; er[n * 4 + t] = red[0][4 + t]; }
}

// ---------- CSR build (batched over relations via blockIdx.y) ----------
__global__ void count_k(const int* __restrict__ dst, int* __restrict__ counts, int E) {
  int r = blockIdx.y;
  int i = blockIdx.x * blockDim.x + threadIdx.x;
  if (i < E) atomicAdd(&counts[r * NMAX + dst[(size_t)r * E + i]], 1);
}

__global__ __launch_bounds__(256) void scan_k(const int* __restrict__ counts,
                                              int* __restrict__ row_ptr, int N) {
  const int* cnt = counts + blockIdx.x * NMAX;
  int* rp = row_ptr + blockIdx.x * (NMAX + 1);
  __shared__ int sums[256];
  int t = threadIdx.x;
  int per = (N + 255) / 256;
  int local[8];
  int base = t * per;
  int s = 0;
  for (int i = 0; i < per; i++) {
    int idx = base + i;
    int v = (idx < N) ? cnt[idx] : 0;
    s += v;
    local[i] = s;
  }
  sums[t] = s;
  __syncthreads();
  for (int off = 1; off < 256; off <<= 1) {
    int v = (t >= off) ? sums[t - off] : 0;
    __syncthreads();
    sums[t] += v;
    __syncthreads();
  }
  int offset = (t > 0) ? sums[t - 1] : 0;
  for (int i = 0; i < per; i++) {
    int idx = base + i;
    if (idx < N) rp[idx + 1] = offset + local[i];
  }
  if (t == 0) rp[0] = 0;
}

__global__ void scatter_k(const int* __restrict__ dst, int* __restrict__ cnt,
                          const int* __restrict__ row_ptr, int* __restrict__ edge_ord,
                          int E) {
  int r = blockIdx.y;
  int i = blockIdx.x * blockDim.x + threadIdx.x;
  if (i < E) {
    int d = dst[(size_t)r * E + i];
    int off = atomicAdd(&cnt[r * NMAX + d], 1);
    edge_ord[(size_t)r * EMAX + row_ptr[r * (NMAX + 1) + d] + off] = i;
  }
}

// ---------- fused edge softmax: per (gnode, head), CSR walk, no atomics ----------
__global__ void sm_k(const int* __restrict__ sp0, const int* __restrict__ sp1,
                     const int* __restrict__ sp2,
                     const int* __restrict__ row_ptr, const int* __restrict__ edge_ord,
                     const float* __restrict__ el, const float* __restrict__ er,
                     float* __restrict__ p, float* __restrict__ rinv, int r) {
  int i = blockIdx.x * 256 + threadIdx.x;  // 0 .. NTOT*4-1
  int gnode = i >> 2, h = i & 3;
  int g = (gnode < 2048) ? (gnode >> 10) : 2;
  int goff = (g == 2) ? 2048 : (g << 10);
  int n = gnode - goff;
  const int* rp = row_ptr + (g * RREL + r) * (NMAX + 1);
  int start = rp[n], end = rp[n + 1];
  float rv = 0.f;
  if (end > start) {
    const int* eo = edge_ord + ((size_t)g * RREL + r) * EMAX;
    const int* srcg = (g == 0) ? sp0 : (g == 1) ? sp1 : sp2;
    float erv = er[gnode * 4 + h];
    float m = -3.4e38f;
    for (int c = start; c < end; c++) {
      float v = el[(goff + srcg[eo[c]]) * 4 + h] + erv;
      v = v > 0.f ? v : 0.2f * v;
      m = fmaxf(m, v);
    }
    float s = 0.f;
    float* pg = p + (size_t)g * EMAX * 4;
    for (int c = start; c < end; c++) {
      int eid = eo[c];
      float v = el[(goff + srcg[eid]) * 4 + h] + erv;
      v = v > 0.f ? v : 0.2f * v;
      float pv = expf(v - m);
      pg[eid * 4 + h] = pv;
      s += pv;
    }
    rv = 1.f / s;
  }
  rinv[gnode * 4 + h] = rv;
}

// ---------- aggregation (grid = NTOT nodes; one relation per launch) ----------
__global__ __launch_bounds__(256) void agg_k(const ushortT* __restrict__ featb,
                                             const float* __restrict__ p,
                                             const float* __restrict__ rinv,
                                             const int* __restrict__ row_ptr,
                                             const int* __restrict__ edge_ord,
                                             const int* __restrict__ sp0,
                                             const int* __restrict__ sp1,
                                             const int* __restrict__ sp2,
                                             float* __restrict__ acc, int r) {
  int gnode = blockIdx.x;
  int g = (gnode < 2048) ? (gnode >> 10) : 2;
  int goff = (g == 2) ? 2048 : (g << 10);
  int n = gnode - goff;
  const int* rp = row_ptr + (g * RREL + r) * (NMAX + 1);
  int start = rp[n], end = rp[n + 1];
  if (end == start) return;
  const int* eo = edge_ord + ((size_t)g * RREL + r) * EMAX;
  const int* srcg = (g == 0) ? sp0 : (g == 1) ? sp1 : sp2;
  const float* pg = p + (size_t)g * EMAX * 4;
  __shared__ int s_src[256];
  __shared__ float s_al[256][4];
  int t = threadIdx.x;
  float o0[8] = {}, o1[8] = {};
  for (int c = start; c < end; c += 256) {
    int m = min(256, end - c);
    if (t < m) {
      int eid = eo[c + t];
      s_src[t] = srcg[eid];
#pragma unroll
      for (int h = 0; h < 4; h++) s_al[t][h] = pg[eid * 4 + h];
    }
    __syncthreads();
    for (int i = 0; i < m; i++) {
      const unsigned* frow = (const unsigned*)(featb + (size_t)(goff + s_src[i]) * HID);
      float a0 = s_al[i][0], a1 = s_al[i][1], a2 = s_al[i][2], a3 = s_al[i][3];
#pragma unroll
      for (int j = 0; j < 8; j++) {
        unsigned u = frow[j * 256 + t];
        float av = (j < 2) ? a0 : (j < 4) ? a1 : (j < 6) ? a2 : a3;
        o0[j] += av * b2f_lo(u);
        o1[j] += av * b2f_hi(u);
      }
    }
    __syncthreads();
  }
  float rv[4];
#pragma unroll
  for (int h = 0; h < 4; h++) rv[h] = rinv[gnode * 4 + h];
#pragma unroll
  for (int j = 0; j < 8; j++) {
    float sc = rv[j >> 1];
    float2* pa = (float2*)(acc + (size_t)gnode * HID + (size_t)(j * 256 + t) * 2);
    float2 v = *pa;
    v.x += o0[j] * sc;
    v.y += o1[j] * sc;
    *pa = v;
  }
}

// ---------- finalize layer1: hb = bf16(elu((acc + sum_r b1)/4)) ----------
__global__ __launch_bounds__(256) void finalize1_k(const float* __restrict__ acc,
                                                   const float* __restrict__ b1,
                                                   ushortT* __restrict__ hb, int total) {
  int i = blockIdx.x * 256 + threadIdx.x;
  if (i >= total) return;
  int col = i & (HID - 1);
  float bs = b1[col] + b1[HID + col] + b1[2 * HID + col] + b1[3 * HID + col];
  float v = (acc[i] + bs) * 0.25f;
  v = v > 0.f ? v : (expf(v) - 1.f);
  hb[i] = f2b(v);
}

// ---------- finalize layer2 + column mean ----------
__global__ __launch_bounds__(256) void finalize2_mean_k(const float* __restrict__ acc,
                                                        const ushortT* __restrict__ hb,
                                                        const float* __restrict__ b2,
                                                        float* __restrict__ gm, int Nn,
                                                        float invN) {
  int col = blockIdx.x * 256 + threadIdx.x;
  int r0 = blockIdx.y * 32;
  int r1 = min(r0 + 32, Nn);
  float bs = 0.25f * (b2[col] + b2[HID + col] + b2[2 * HID + col] + b2[3 * HID + col]);
  float p = 0.f;
  for (int r = r0; r < r1; r++) {
    size_t i = (size_t)r * HID + col;
    p += acc[i] * 0.25f + b2f1(hb[i]) + bs;
  }
  atomicAdd(&gm[col], p * invN);
}

// ---------- readout MLP ----------
__global__ void initvec_k(float* __restrict__ out, const float* __restrict__ b, int n) {
  int i = blockIdx.x * blockDim.x + threadIdx.x;
  if (i < n) out[i] = b[i];
}

__global__ __launch_bounds__(256) void matvec_k(const float* __restrict__ v,
                                                const float* __restrict__ W,
                                                float* __restrict__ out, int K, int Nout,
                                                int kchunk) {
  int j = blockIdx.x * 256 + threadIdx.x;
  if (j >= Nout) return;
  int k0 = blockIdx.y * kchunk;
  int k1 = min(k0 + kchunk, K);
  float p = 0.f;
  for (int k = k0; k < k1; k++) p += v[k] * W[(size_t)k * Nout + j];
  atomicAdd(&out[j], p);
}

__global__ __launch_bounds__(256) void final_k(const float* __restrict__ hc,
                                               const float* __restrict__ Wc2,
                                               const float* __restrict__ bc2,
                                               float* __restrict__ out) {
  __shared__ float red[256];
  int t = threadIdx.x;
  for (int c = 0; c < 3; c++) {
    float p = 0.f;
    for (int k = t; k < 1024; k += 256) {
      float v = hc[k];
      v = v > 0.f ? v : 0.f;
      p += v * Wc2[k * 3 + c];
    }
    red[t] = p;
    __syncthreads();
    for (int s = 128; s > 0; s >>= 1) {
      if (t < s) red[t] += red[t + s];
      __syncthreads();
    }
    if (t == 0) out[c] = red[0] + bc2[c];
    __syncthreads();
  }
}

// ================= host side =================
extern "C" void kernel_launch(void* const* d_in, const int* in_sizes, int n_in,
                              void* d_out, int out_size, void* d_ws, size_t ws_size,
                              hipStream_t stream) {
  const float* x_pre = (const float*)d_in[0];
  const float* x_hyp = (const float*)d_in[1];
  const float* x_comb = (const float*)d_in[2];
  const int* src_pre = (const int*)d_in[3];
  const int* dst_pre = (const int*)d_in[4];
  const int* src_hyp = (const int*)d_in[5];
  const int* dst_hyp = (const int*)d_in[6];
  const int* src_comb = (const int*)d_in[7];
  const int* dst_comb = (const int*)d_in[8];
  const float* W1 = (const float*)d_in[9];
  const float* al1 = (const float*)d_in[10];
  const float* ar1 = (const float*)d_in[11];
  const float* b1 = (const float*)d_in[12];
  const float* res1 = (const float*)d_in[13];
  const float* W2 = (const float*)d_in[14];
  const float* al2 = (const float*)d_in[15];
  const float* ar2 = (const float*)d_in[16];
  const float* b2 = (const float*)d_in[17];
  const float* Wp = (const float*)d_in[18];
  const float* bp = (const float*)d_in[19];
  const float* Wc1 = (const float*)d_in[20];
  const float* bc1 = (const float*)d_in[21];
  const float* Wc2 = (const float*)d_in[22];
  const float* bc2 = (const float*)d_in[23];
  float* out = (float*)d_out;

  char* w = (char*)d_ws;
  size_t off = 0;
  auto alloc = [&](size_t bytes) -> void* {
    void* p = w + off;
    off = (off + bytes + 255) & ~(size_t)255;
    return p;
  };
  float* acc = (float*)alloc((size_t)NTOT * HID * 4);        // 64 MB
  ushortT* hb = (ushortT*)alloc((size_t)NTOT * HID * 2);     // 32 MB
  ushortT* featb = (ushortT*)alloc((size_t)NTOT * HID * 2);  // 32 MB
  ushortT* xb = (ushortT*)alloc((size_t)NTOT * 1024 * 2);    // 8 MB
  ushortT* Wt = (ushortT*)alloc((size_t)HID * HID * 2);      // 32 MB
  float* el = (float*)alloc(NTOT * 4 * 4);
  float* er = (float*)alloc(NTOT * 4 * 4);
  float* pbuf = (float*)alloc((size_t)3 * EMAX * 4 * 4);
  float* rinv = (float*)alloc(NTOT * 4 * 4);
  int* row_ptr = (int*)alloc(3 * RREL * (NMAX + 1) * 4);
  int* edge_ord = (int*)alloc((size_t)3 * RREL * EMAX * 4);
  int* counts = (int*)alloc(RREL * NMAX * 4);
  float* gm = (float*)alloc(3 * HID * 4);
  float* z = (float*)alloc(3072 * 4);
  float* hc = (float*)alloc(1024 * 4);

  hipMemsetAsync(gm, 0, 3 * HID * 4, stream);

  struct GDesc { const float* x; const int* src; const int* dst; int N; int E; int goff; };
  GDesc gs[3] = {{x_pre, src_pre, dst_pre, 1024, 8192, 0},
                 {x_hyp, src_hyp, dst_hyp, 1024, 8192, 1024},
                 {x_comb, src_comb, dst_comb, 2048, 16384, 2048}};

  // CSR per (graph, relation)
  for (int g = 0; g < 3; g++) {
    int N = gs[g].N, E = gs[g].E;
    int eb = E / 256;
    int* rpG = row_ptr + g * RREL * (NMAX + 1);
    int* eoG = edge_ord + (size_t)g * RREL * EMAX;
    hipMemsetAsync(counts, 0, RREL * NMAX * 4, stream);
    count_k<<<dim3(eb, RREL), 256, 0, stream>>>(gs[g].dst, counts, E);
    scan_k<<<RREL, 256, 0, stream>>>(counts, rpG, N);
    hipMemsetAsync(counts, 0, RREL * NMAX * 4, stream);
    scatter_k<<<dim3(eb, RREL), 256, 0, stream>>>(gs[g].dst, counts, rpG, eoG, E);
  }

  // x -> bf16, node-batched layout
  for (int g = 0; g < 3; g++)
    f2b_k<<<gs[g].N * 1024 / 8 / 256, 256, 0, stream>>>(gs[g].x,
                                                        xb + (size_t)gs[g].goff * 1024,
                                                        gs[g].N * 1024 / 8);

  for (int layer = 0; layer < 2; layer++) {
    int K = (layer == 0) ? 1024 : HID;
    const ushortT* Ab = (layer == 0) ? xb : hb;
    const float* Wl = (layer == 0) ? W1 : W2;
    const float* all = (layer == 0) ? al1 : al2;
    const float* arl = (layer == 0) ? ar1 : ar2;
    dim3 convGrid(HID / 32, K / 32);

    if (layer == 0) {
      // acc = x @ (sum_r res1_r): one GEMM inits acc (no memset)
      convtsum_k<<<convGrid, 256, 0, stream>>>(res1, Wt, 1024);
      gemm256<<<256, 512, 0, stream>>>(xb, Wt, acc, (ushortT*)nullptr, 1024, 0);
    } else {
      hipMemsetAsync(acc, 0, (size_t)NTOT * HID * 4, stream);
    }

    for (int r = 0; r < RREL; r++) {
      convt_k<<<convGrid, 256, 0, stream>>>(Wl + (size_t)r * K * HID, Wt, K);
      gemm256<<<256, 512, 0, stream>>>(Ab, Wt, (float*)nullptr, featb, K, 2);
      el_er_k<<<NTOT, 256, 0, stream>>>(featb, all + r * HID, arl + r * HID, el, er);
      const int* sp0 = src_pre + (size_t)r * 8192;
      const int* sp1 = src_hyp + (size_t)r * 8192;
      const int* sp2 = src_comb + (size_t)r * 16384;
      sm_k<<<NTOT * 4 / 256, 256, 0, stream>>>(sp0, sp1, sp2, row_ptr, edge_ord, el, er,
                                               pbuf, rinv, r);
      agg_k<<<NTOT, 256, 0, stream>>>(featb, pbuf, rinv, row_ptr, edge_ord, sp0, sp1, sp2,
                                      acc, r);
    }

    if (layer == 0) {
      finalize1_k<<<(size_t)NTOT * HID / 256, 256, 0, stream>>>(acc, b1, hb, NTOT * HID);
    } else {
      for (int g = 0; g < 3; g++) {
        dim3 fg(HID / 256, (gs[g].N + 31) / 32);
        finalize2_mean_k<<<fg, 256, 0, stream>>>(acc + (size_t)gs[g].goff * HID,
                                                 hb + (size_t)gs[g].goff * HID, b2,
                                                 gm + g * HID, gs[g].N, 1.0f / gs[g].N);
      }
    }
  }

  // readout MLP (fp32)
  initvec_k<<<12, 256, 0, stream>>>(z, bp, 3072);
  {
    dim3 mg(3072 / 256, 48);
    matvec_k<<<mg, 256, 0, stream>>>(gm, Wp, z, 12288, 3072, 256);
  }
  initvec_k<<<4, 256, 0, stream>>>(hc, bc1, 1024);
  {
    dim3 mg(1024 / 256, 24);
    matvec_k<<<mg, 256, 0, stream>>>(z, Wc1, hc, 3072, 1024, 128);
  }
  final_k<<<1, 256, 0, stream>>>(hc, Wc2, bc2, out);
}

// Round 3
// 2014.390 us; speedup vs baseline: 2.1878x; 1.0832x over previous
//
#include <hip/hip_runtime.h>
#include <math.h>

#define HID 4096
#define NMAX 2048
#define EMAX 16384
#define RREL 4
#define NTOT 4096   // 1024 (pre) + 1024 (hyp) + 2048 (comb), node-batched
#define NCOL 16384  // 4 relations x 4096, relation-batched GEMM width

typedef unsigned short ushortT;
typedef __attribute__((ext_vector_type(8))) short short8;
typedef __attribute__((ext_vector_type(4))) float floatx4;

// async global->LDS, 16B per lane (dest = wave-uniform base + lane*16)
#define GLDS(gp, lp)                                                                        \
  __builtin_amdgcn_global_load_lds((const __attribute__((address_space(1))) unsigned*)(gp), \
                                   (__attribute__((address_space(3))) unsigned*)(lp), 16, 0, 0)

// ---------- helpers ----------
__device__ __forceinline__ ushortT f2b(float f) {  // fp32 -> bf16 RNE
  unsigned u = __float_as_uint(f);
  u = u + 0x7fffu + ((u >> 16) & 1u);
  return (ushortT)(u >> 16);
}
__device__ __forceinline__ float b2f_lo(unsigned u) { return __uint_as_float(u << 16); }
__device__ __forceinline__ float b2f_hi(unsigned u) { return __uint_as_float(u & 0xffff0000u); }
__device__ __forceinline__ float b2f1(ushortT u) { return __uint_as_float((unsigned)u << 16); }

// ---------- weight convert + transpose: W[K][4096] fp32 -> Wt[4096][K] bf16 ----------
__global__ __launch_bounds__(256) void convt_k(const float* __restrict__ W,
                                               ushortT* __restrict__ Wt, int K) {
  int bn = blockIdx.x * 32;  // column (n) tile of W
  int bk = blockIdx.y * 32;  // row (k) tile of W
  int t = threadIdx.x;
  __shared__ ushortT tile[32][40];  // [n][k]
  int kr = t >> 3;
  int nc = (t & 7) * 4;
  float4 v = *(const float4*)(W + (size_t)(bk + kr) * 4096 + bn + nc);
  tile[nc + 0][kr] = f2b(v.x);
  tile[nc + 1][kr] = f2b(v.y);
  tile[nc + 2][kr] = f2b(v.z);
  tile[nc + 3][kr] = f2b(v.w);
  __syncthreads();
  int n = t >> 3, j = (t & 7) * 4;
  uint2 u;
  u.x = (unsigned)tile[n][j] | ((unsigned)tile[n][j + 1] << 16);
  u.y = (unsigned)tile[n][j + 2] | ((unsigned)tile[n][j + 3] << 16);
  *(uint2*)(Wt + (size_t)(bn + n) * K + bk + j) = u;
}

// ---------- sum 4 relation residual mats then convert+transpose (K=1024) ----------
__global__ __launch_bounds__(256) void convtsum_k(const float* __restrict__ W,
                                                  ushortT* __restrict__ Wt, int K) {
  int bn = blockIdx.x * 32;
  int bk = blockIdx.y * 32;
  int t = threadIdx.x;
  __shared__ ushortT tile[32][40];
  int kr = t >> 3;
  int nc = (t & 7) * 4;
  const size_t S = (size_t)1024 * HID;
  size_t base = (size_t)(bk + kr) * 4096 + bn + nc;
  float4 v0 = *(const float4*)(W + base);
  float4 v1 = *(const float4*)(W + base + S);
  float4 v2 = *(const float4*)(W + base + 2 * S);
  float4 v3 = *(const float4*)(W + base + 3 * S);
  tile[nc + 0][kr] = f2b(v0.x + v1.x + v2.x + v3.x);
  tile[nc + 1][kr] = f2b(v0.y + v1.y + v2.y + v3.y);
  tile[nc + 2][kr] = f2b(v0.z + v1.z + v2.z + v3.z);
  tile[nc + 3][kr] = f2b(v0.w + v1.w + v2.w + v3.w);
  __syncthreads();
  int n = t >> 3, j = (t & 7) * 4;
  uint2 u;
  u.x = (unsigned)tile[n][j] | ((unsigned)tile[n][j + 1] << 16);
  u.y = (unsigned)tile[n][j + 2] | ((unsigned)tile[n][j + 3] << 16);
  *(uint2*)(Wt + (size_t)(bn + n) * K + bk + j) = u;
}

// ---------- plain fp32 -> bf16 convert ----------
__global__ void f2b_k(const float* __restrict__ in, ushortT* __restrict__ out, int n8) {
  int i = blockIdx.x * 256 + threadIdx.x;
  if (i >= n8) return;
  const float4* p = (const float4*)in;
  float4 a = p[2 * i], b = p[2 * i + 1];
  uint4 u;
  u.x = (unsigned)f2b(a.x) | ((unsigned)f2b(a.y) << 16);
  u.y = (unsigned)f2b(a.z) | ((unsigned)f2b(a.w) << 16);
  u.z = (unsigned)f2b(b.x) | ((unsigned)f2b(b.y) << 16);
  u.w = (unsigned)f2b(b.z) | ((unsigned)f2b(b.w) << 16);
  *(uint4*)(out + 8 * i) = u;
}

// ---------- 256x256-tile 4-phase bf16 MFMA GEMM ----------
// 8 waves (2M x 4N), BK=32, double-buffered 64KB LDS, XOR swizzle,
// counted vmcnt (never 0 in steady state), raw s_barrier, setprio around MFMA.
// grid.x = 16 * nbx blocks (M fixed 4096, N = nbx*256); ldc = C row stride
// mode 0: C = (fp32)    mode 2: Cb = (bf16)
#define MIDB()                                         \
  __builtin_amdgcn_s_barrier();                        \
  asm volatile("s_waitcnt lgkmcnt(0)" ::: "memory");   \
  __builtin_amdgcn_sched_barrier(0);                   \
  __builtin_amdgcn_s_setprio(1)

#define RD_A(BASE, MH)                                                              \
  _Pragma("unroll") for (int f = 0; f < 4; f++)                                     \
      a[f] = *(const short8*)&lds[(BASE) + (wm * 128 + (MH)*64 + f * 16 + lrow) * 32 + kcol];
#define RD_B(BASE)                                                                  \
  _Pragma("unroll") for (int n = 0; n < 4; n++)                                     \
      b[n] = *(const short8*)&lds[(BASE) + 8192 + (wn * 64 + n * 16 + lrow) * 32 + kcol];
#define MFMA_H(MH)                                                                  \
  _Pragma("unroll") for (int f = 0; f < 4; f++)                                     \
  _Pragma("unroll") for (int n = 0; n < 4; n++)                                     \
      acc[(MH)*4 + f][n] =                                                          \
          __builtin_amdgcn_mfma_f32_16x16x32_bf16(a[f], b[n], acc[(MH)*4 + f][n], 0, 0, 0);
#define SA(BUF, H, KT) GLDS(Asrc + (size_t)((H)*128) * K + (KT)*32, lds + (BUF)*16384 + (H)*4096 + t * 8)
#define SB(BUF, H, KT) GLDS(Bsrc + (size_t)((H)*128) * K + (KT)*32, lds + (BUF)*16384 + 8192 + (H)*4096 + t * 8)

__global__ __launch_bounds__(512, 1) void gemm256(const ushortT* __restrict__ A,
                                                  const ushortT* __restrict__ Bt,
                                                  float* __restrict__ C,
                                                  ushortT* __restrict__ Cb,
                                                  int K, int ldc, int nbx, int mode) {
  __shared__ ushortT lds[32768];  // [2 buf][A 8192 | B 8192] elems = 64 KB
  const int t = threadIdx.x;
  // bijective XCD-aware swizzle (nwg = 16*nbx, nwg%8==0)
  int bid = blockIdx.x;
  int cpx = (nbx << 4) >> 3;
  int swz = (bid & 7) * cpx + (bid >> 3);
  const int row0 = (swz / nbx) * 256;
  const int col0 = (swz % nbx) * 256;

  // staging source: linear LDS dest + inverse-swizzled global source (rule 21)
  const int rA = t >> 2;
  const int c8l = ((t & 3) ^ (((t >> 5) & 1) << 1)) * 8;
  const ushortT* Asrc = A + (size_t)(row0 + rA) * K + c8l;
  const ushortT* Bsrc = Bt + (size_t)(col0 + rA) * K + c8l;

  const int wave = t >> 6, lane = t & 63;
  const int wm = wave >> 2, wn = wave & 3;  // 2 x 4 wave grid
  const int lrow = lane & 15, lkg = lane >> 4;
  const int kcol = (lkg * 8) ^ (((lane >> 3) & 1) << 4);  // swizzled read col

  floatx4 acc[8][4];
#pragma unroll
  for (int f = 0; f < 8; f++)
#pragma unroll
    for (int n = 0; n < 4; n++) acc[f][n] = (floatx4){0.f, 0.f, 0.f, 0.f};
  short8 a[4], b[4];

  const int nT = K >> 5;
  const int nIt = nT >> 1;

  // prologue: K0 full -> buf0; K1.B -> buf1
  SA(0, 0, 0); SA(0, 1, 0); SB(0, 0, 0); SB(0, 1, 0);
  SB(1, 0, 1); SB(1, 1, 1);
  asm volatile("s_waitcnt vmcnt(2)" ::: "memory");
  __builtin_amdgcn_s_barrier();
  __builtin_amdgcn_sched_barrier(0);

#pragma unroll 1
  for (int it = 0; it < nIt; it++) {
    const int k1 = 2 * it + 1, k2 = 2 * it + 2, k3 = 2 * it + 3;
    const bool s2 = (k2 < nT), s3 = (k3 < nT);
    // ---- P1: buf0 mh0 ----
    RD_A(0, 0); RD_B(0);
    SA(1, 0, k1); SA(1, 1, k1);
    MIDB();
    MFMA_H(0);
    __builtin_amdgcn_s_setprio(0);
    __builtin_amdgcn_s_barrier();
    __builtin_amdgcn_sched_barrier(0);
    // ---- P2: buf0 mh1 ----
    RD_A(0, 1);
    if (s2) { SB(0, 0, k2); SB(0, 1, k2); }
    MIDB();
    MFMA_H(1);
    __builtin_amdgcn_s_setprio(0);
    if (s2) asm volatile("s_waitcnt vmcnt(2)" ::: "memory");
    else    asm volatile("s_waitcnt vmcnt(0)" ::: "memory");
    __builtin_amdgcn_s_barrier();
    __builtin_amdgcn_sched_barrier(0);
    // ---- P3: buf1 mh0 ----
    RD_A(16384, 0); RD_B(16384);
    if (s2) { SA(0, 0, k2); SA(0, 1, k2); }
    MIDB();
    MFMA_H(0);
    __builtin_amdgcn_s_setprio(0);
    __builtin_amdgcn_s_barrier();
    __builtin_amdgcn_sched_barrier(0);
    // ---- P4: buf1 mh1 ----
    RD_A(16384, 1);
    if (s3) { SB(1, 0, k3); SB(1, 1, k3); }
    MIDB();
    MFMA_H(1);
    __builtin_amdgcn_s_setprio(0);
    if (s3) asm volatile("s_waitcnt vmcnt(2)" ::: "memory");
    else    asm volatile("s_waitcnt vmcnt(0)" ::: "memory");
    __builtin_amdgcn_s_barrier();
    __builtin_amdgcn_sched_barrier(0);
  }

  // epilogue: C/D layout col=lane&15, row=(lane>>4)*4+reg
#pragma unroll
  for (int fr = 0; fr < 8; fr++) {
    int row = row0 + wm * 128 + fr * 16 + lkg * 4;
#pragma unroll
    for (int n = 0; n < 4; n++) {
      int col = col0 + wn * 64 + n * 16 + lrow;
#pragma unroll
      for (int j = 0; j < 4; j++) {
        size_t idx = (size_t)(row + j) * ldc + col;
        if (mode == 0) C[idx] = acc[fr][n][j];
        else Cb[idx] = f2b(acc[fr][n][j]);
      }
    }
  }
}

// ---------- el/er from bf16 feat4 (grid = NTOT x RREL) ----------
__global__ __launch_bounds__(256) void el_er_k(const ushortT* __restrict__ featb4,
                                               const float* __restrict__ al,
                                               const float* __restrict__ ar,
                                               float* __restrict__ el,
                                               float* __restrict__ er) {
  int n = blockIdx.x, r = blockIdx.y, t = threadIdx.x;
  const unsigned* row = (const unsigned*)(featb4 + (size_t)n * NCOL + r * HID);
  const float* alr = al + r * HID;
  const float* arr = ar + r * HID;
  float pel[4] = {}, per_[4] = {};
#pragma unroll
  for (int j = 0; j < 8; j++) {
    unsigned u = row[j * 256 + t];
    int col = (j * 256 + t) * 2;
    const int h = j >> 1;
    pel[h] += b2f_lo(u) * alr[col] + b2f_hi(u) * alr[col + 1];
    per_[h] += b2f_lo(u) * arr[col] + b2f_hi(u) * arr[col + 1];
  }
  __shared__ float red[256][9];
#pragma unroll
  for (int h = 0; h < 4; h++) { red[t][h] = pel[h]; red[t][4 + h] = per_[h]; }
  __syncthreads();
  for (int s = 128; s > 0; s >>= 1) {
    if (t < s)
#pragma unroll
      for (int j = 0; j < 8; j++) red[t][j] += red[t + s][j];
    __syncthreads();
  }
  if (t < 4) {
    el[((size_t)r * NTOT + n) * 4 + t] = red[0][t];
    er[((size_t)r * NTOT + n) * 4 + t] = red[0][4 + t];
  }
}

// ---------- CSR build (batched over relations via blockIdx.y) ----------
__global__ void count_k(const int* __restrict__ dst, int* __restrict__ counts, int E) {
  int r = blockIdx.y;
  int i = blockIdx.x * blockDim.x + threadIdx.x;
  if (i < E) atomicAdd(&counts[r * NMAX + dst[(size_t)r * E + i]], 1);
}

__global__ __launch_bounds__(256) void scan_k(const int* __restrict__ counts,
                                              int* __restrict__ row_ptr, int N) {
  const int* cnt = counts + blockIdx.x * NMAX;
  int* rp = row_ptr + blockIdx.x * (NMAX + 1);
  __shared__ int sums[256];
  int t = threadIdx.x;
  int per = (N + 255) / 256;
  int local[8];
  int base = t * per;
  int s = 0;
  for (int i = 0; i < per; i++) {
    int idx = base + i;
    int v = (idx < N) ? cnt[idx] : 0;
    s += v;
    local[i] = s;
  }
  sums[t] = s;
  __syncthreads();
  for (int off = 1; off < 256; off <<= 1) {
    int v = (t >= off) ? sums[t - off] : 0;
    __syncthreads();
    sums[t] += v;
    __syncthreads();
  }
  int offset = (t > 0) ? sums[t - 1] : 0;
  for (int i = 0; i < per; i++) {
    int idx = base + i;
    if (idx < N) rp[idx + 1] = offset + local[i];
  }
  if (t == 0) rp[0] = 0;
}

__global__ void scatter_k(const int* __restrict__ dst, int* __restrict__ cnt,
                          const int* __restrict__ row_ptr, int* __restrict__ edge_ord,
                          int E) {
  int r = blockIdx.y;
  int i = blockIdx.x * blockDim.x + threadIdx.x;
  if (i < E) {
    int d = dst[(size_t)r * E + i];
    int off = atomicAdd(&cnt[r * NMAX + d], 1);
    edge_ord[(size_t)r * EMAX + row_ptr[r * (NMAX + 1) + d] + off] = i;
  }
}

// ---------- fused edge softmax (r = blockIdx.y): CSR walk, no atomics ----------
__global__ void sm_k(const int* __restrict__ sp0, const int* __restrict__ sp1,
                     const int* __restrict__ sp2,
                     const int* __restrict__ row_ptr, const int* __restrict__ edge_ord,
                     const float* __restrict__ el, const float* __restrict__ er,
                     float* __restrict__ p, float* __restrict__ rinv) {
  int r = blockIdx.y;
  int i = blockIdx.x * 256 + threadIdx.x;  // 0 .. NTOT*4-1
  int gnode = i >> 2, h = i & 3;
  int g = (gnode < 2048) ? (gnode >> 10) : 2;
  int goff = (g == 2) ? 2048 : (g << 10);
  int n = gnode - goff;
  const int* rp = row_ptr + (g * RREL + r) * (NMAX + 1);
  int start = rp[n], end = rp[n + 1];
  float rv = 0.f;
  if (end > start) {
    const int* eo = edge_ord + ((size_t)g * RREL + r) * EMAX;
    const int* srcg = (g == 0) ? sp0 + (size_t)r * 8192
                    : (g == 1) ? sp1 + (size_t)r * 8192
                               : sp2 + (size_t)r * 16384;
    const float* elr = el + (size_t)r * NTOT * 4;
    float erv = er[((size_t)r * NTOT + gnode) * 4 + h];
    float m = -3.4e38f;
    for (int c = start; c < end; c++) {
      float v = elr[(goff + srcg[eo[c]]) * 4 + h] + erv;
      v = v > 0.f ? v : 0.2f * v;
      m = fmaxf(m, v);
    }
    float s = 0.f;
    float* pg = p + (size_t)(r * 3 + g) * EMAX * 4;
    for (int c = start; c < end; c++) {
      int eid = eo[c];
      float v = elr[(goff + srcg[eid]) * 4 + h] + erv;
      v = v > 0.f ? v : 0.2f * v;
      float pv = expf(v - m);
      pg[eid * 4 + h] = pv;
      s += pv;
    }
    rv = 1.f / s;
  }
  rinv[((size_t)r * NTOT + gnode) * 4 + h] = rv;
}

// ---------- aggregation over ALL 4 relations, one acc pass (grid = NTOT) ----------
// accmode 1: acc += (layer0, residual preloaded)   0: acc = (layer1, no memset)
__global__ __launch_bounds__(256) void agg4_k(const ushortT* __restrict__ featb4,
                                              const float* __restrict__ p,
                                              const float* __restrict__ rinv,
                                              const int* __restrict__ row_ptr,
                                              const int* __restrict__ edge_ord,
                                              const int* __restrict__ sp0,
                                              const int* __restrict__ sp1,
                                              const int* __restrict__ sp2,
                                              float* __restrict__ acc, int accmode) {
  int gnode = blockIdx.x;
  int g = (gnode < 2048) ? (gnode >> 10) : 2;
  int goff = (g == 2) ? 2048 : (g << 10);
  int n = gnode - goff;
  __shared__ int s_src[256];
  __shared__ float s_al[256][4];
  int t = threadIdx.x;
  float o0[8] = {}, o1[8] = {};
  for (int r = 0; r < RREL; r++) {
    const int* rp = row_ptr + (g * RREL + r) * (NMAX + 1);
    int start = rp[n], end = rp[n + 1];
    if (end == start) continue;
    const int* eo = edge_ord + ((size_t)g * RREL + r) * EMAX;
    const int* srcg = (g == 0) ? sp0 + (size_t)r * 8192
                    : (g == 1) ? sp1 + (size_t)r * 8192
                               : sp2 + (size_t)r * 16384;
    const float* pg = p + (size_t)(r * 3 + g) * EMAX * 4;
    const float* rvp = rinv + ((size_t)r * NTOT + gnode) * 4;
    float rv0 = rvp[0], rv1 = rvp[1], rv2 = rvp[2], rv3 = rvp[3];
    const ushortT* fb = featb4 + (size_t)r * HID;
    for (int c = start; c < end; c += 256) {
      int m = min(256, end - c);
      if (t < m) {
        int eid = eo[c + t];
        s_src[t] = srcg[eid];
        s_al[t][0] = pg[eid * 4 + 0] * rv0;
        s_al[t][1] = pg[eid * 4 + 1] * rv1;
        s_al[t][2] = pg[eid * 4 + 2] * rv2;
        s_al[t][3] = pg[eid * 4 + 3] * rv3;
      }
      __syncthreads();
      for (int i = 0; i < m; i++) {
        const unsigned* frow = (const unsigned*)(fb + (size_t)(goff + s_src[i]) * NCOL);
        float a0 = s_al[i][0], a1 = s_al[i][1], a2 = s_al[i][2], a3 = s_al[i][3];
#pragma unroll
        for (int j = 0; j < 8; j++) {
          unsigned u = frow[j * 256 + t];
          float av = (j < 2) ? a0 : (j < 4) ? a1 : (j < 6) ? a2 : a3;
          o0[j] += av * b2f_lo(u);
          o1[j] += av * b2f_hi(u);
        }
      }
      __syncthreads();
    }
  }
#pragma unroll
  for (int j = 0; j < 8; j++) {
    float2* pa = (float2*)(acc + (size_t)gnode * HID + (size_t)(j * 256 + t) * 2);
    if (accmode) {
      float2 v = *pa;
      v.x += o0[j];
      v.y += o1[j];
      *pa = v;
    } else {
      float2 v;
      v.x = o0[j];
      v.y = o1[j];
      *pa = v;
    }
  }
}

// ---------- finalize layer1: hb = bf16(elu((acc + sum_r b1)/4)) ----------
__global__ __launch_bounds__(256) void finalize1_k(const float* __restrict__ acc,
                                                   const float* __restrict__ b1,
                                                   ushortT* __restrict__ hb, int total) {
  int i = blockIdx.x * 256 + threadIdx.x;
  if (i >= total) return;
  int col = i & (HID - 1);
  float bs = b1[col] + b1[HID + col] + b1[2 * HID + col] + b1[3 * HID + col];
  float v = (acc[i] + bs) * 0.25f;
  v = v > 0.f ? v : (expf(v) - 1.f);
  hb[i] = f2b(v);
}

// ---------- finalize layer2 + column mean ----------
__global__ __launch_bounds__(256) void finalize2_mean_k(const float* __restrict__ acc,
                                                        const ushortT* __restrict__ hb,
                                                        const float* __restrict__ b2,
                                                        float* __restrict__ gm, int Nn,
                                                        float invN) {
  int col = blockIdx.x * 256 + threadIdx.x;
  int r0 = blockIdx.y * 32;
  int r1 = min(r0 + 32, Nn);
  float bs = 0.25f * (b2[col] + b2[HID + col] + b2[2 * HID + col] + b2[3 * HID + col]);
  float p = 0.f;
  for (int r = r0; r < r1; r++) {
    size_t i = (size_t)r * HID + col;
    p += acc[i] * 0.25f + b2f1(hb[i]) + bs;
  }
  atomicAdd(&gm[col], p * invN);
}

// ---------- readout MLP ----------
__global__ void initvec_k(float* __restrict__ out, const float* __restrict__ b, int n) {
  int i = blockIdx.x * blockDim.x + threadIdx.x;
  if (i < n) out[i] = b[i];
}

__global__ __launch_bounds__(256) void matvec_k(const float* __restrict__ v,
                                                const float* __restrict__ W,
                                                float* __restrict__ out, int K, int Nout,
                                                int kchunk) {
  int j = blockIdx.x * 256 + threadIdx.x;
  if (j >= Nout) return;
  int k0 = blockIdx.y * kchunk;
  int k1 = min(k0 + kchunk, K);
  float p = 0.f;
  for (int k = k0; k < k1; k++) p += v[k] * W[(size_t)k * Nout + j];
  atomicAdd(&out[j], p);
}

__global__ __launch_bounds__(256) void final_k(const float* __restrict__ hc,
                                               const float* __restrict__ Wc2,
                                               const float* __restrict__ bc2,
                                               float* __restrict__ out) {
  __shared__ float red[256];
  int t = threadIdx.x;
  for (int c = 0; c < 3; c++) {
    float p = 0.f;
    for (int k = t; k < 1024; k += 256) {
      float v = hc[k];
      v = v > 0.f ? v : 0.f;
      p += v * Wc2[k * 3 + c];
    }
    red[t] = p;
    __syncthreads();
    for (int s = 128; s > 0; s >>= 1) {
      if (t < s) red[t] += red[t + s];
      __syncthreads();
    }
    if (t == 0) out[c] = red[0] + bc2[c];
    __syncthreads();
  }
}

// ================= host side =================
extern "C" void kernel_launch(void* const* d_in, const int* in_sizes, int n_in,
                              void* d_out, int out_size, void* d_ws, size_t ws_size,
                              hipStream_t stream) {
  const float* x_pre = (const float*)d_in[0];
  const float* x_hyp = (const float*)d_in[1];
  const float* x_comb = (const float*)d_in[2];
  const int* src_pre = (const int*)d_in[3];
  const int* dst_pre = (const int*)d_in[4];
  const int* src_hyp = (const int*)d_in[5];
  const int* dst_hyp = (const int*)d_in[6];
  const int* src_comb = (const int*)d_in[7];
  const int* dst_comb = (const int*)d_in[8];
  const float* W1 = (const float*)d_in[9];
  const float* al1 = (const float*)d_in[10];
  const float* ar1 = (const float*)d_in[11];
  const float* b1 = (const float*)d_in[12];
  const float* res1 = (const float*)d_in[13];
  const float* W2 = (const float*)d_in[14];
  const float* al2 = (const float*)d_in[15];
  const float* ar2 = (const float*)d_in[16];
  const float* b2 = (const float*)d_in[17];
  const float* Wp = (const float*)d_in[18];
  const float* bp = (const float*)d_in[19];
  const float* Wc1 = (const float*)d_in[20];
  const float* bc1 = (const float*)d_in[21];
  const float* Wc2 = (const float*)d_in[22];
  const float* bc2 = (const float*)d_in[23];
  float* out = (float*)d_out;

  char* w = (char*)d_ws;
  size_t off = 0;
  auto alloc = [&](size_t bytes) -> void* {
    void* p = w + off;
    off = (off + bytes + 255) & ~(size_t)255;
    return p;
  };
  float* acc = (float*)alloc((size_t)NTOT * HID * 4);          // 64 MB
  ushortT* hb = (ushortT*)alloc((size_t)NTOT * HID * 2);       // 32 MB
  ushortT* featb4 = (ushortT*)alloc((size_t)NTOT * NCOL * 2);  // 128 MB
  ushortT* xb = (ushortT*)alloc((size_t)NTOT * 1024 * 2);      // 8 MB
  ushortT* Wt = (ushortT*)alloc((size_t)NCOL * HID * 2);       // 128 MB
  float* el = (float*)alloc((size_t)RREL * NTOT * 4 * 4);
  float* er = (float*)alloc((size_t)RREL * NTOT * 4 * 4);
  float* pbuf = (float*)alloc((size_t)RREL * 3 * EMAX * 4 * 4);
  float* rinv = (float*)alloc((size_t)RREL * NTOT * 4 * 4);
  int* row_ptr = (int*)alloc(3 * RREL * (NMAX + 1) * 4);
  int* edge_ord = (int*)alloc((size_t)3 * RREL * EMAX * 4);
  int* counts = (int*)alloc(RREL * NMAX * 4);
  float* gm = (float*)alloc(3 * HID * 4);
  float* z = (float*)alloc(3072 * 4);
  float* hc = (float*)alloc(1024 * 4);

  hipMemsetAsync(gm, 0, 3 * HID * 4, stream);

  struct GDesc { const float* x; const int* src; const int* dst; int N; int E; int goff; };
  GDesc gs[3] = {{x_pre, src_pre, dst_pre, 1024, 8192, 0},
                 {x_hyp, src_hyp, dst_hyp, 1024, 8192, 1024},
                 {x_comb, src_comb, dst_comb, 2048, 16384, 2048}};

  // CSR per (graph, relation)
  for (int g = 0; g < 3; g++) {
    int N = gs[g].N, E = gs[g].E;
    int eb = E / 256;
    int* rpG = row_ptr + g * RREL * (NMAX + 1);
    int* eoG = edge_ord + (size_t)g * RREL * EMAX;
    hipMemsetAsync(counts, 0, RREL * NMAX * 4, stream);
    count_k<<<dim3(eb, RREL), 256, 0, stream>>>(gs[g].dst, counts, E);
    scan_k<<<RREL, 256, 0, stream>>>(counts, rpG, N);
    hipMemsetAsync(counts, 0, RREL * NMAX * 4, stream);
    scatter_k<<<dim3(eb, RREL), 256, 0, stream>>>(gs[g].dst, counts, rpG, eoG, E);
  }

  // x -> bf16, node-batched layout
  for (int g = 0; g < 3; g++)
    f2b_k<<<gs[g].N * 1024 / 8 / 256, 256, 0, stream>>>(gs[g].x,
                                                        xb + (size_t)gs[g].goff * 1024,
                                                        gs[g].N * 1024 / 8);

  for (int layer = 0; layer < 2; layer++) {
    int K = (layer == 0) ? 1024 : HID;
    const ushortT* Ab = (layer == 0) ? xb : hb;
    const float* Wl = (layer == 0) ? W1 : W2;
    const float* all = (layer == 0) ? al1 : al2;
    const float* arl = (layer == 0) ? ar1 : ar2;
    dim3 convGrid(HID / 32, K / 32);

    if (layer == 0) {
      // acc = x @ (sum_r res1_r): one GEMM inits acc (no memset)
      convtsum_k<<<convGrid, 256, 0, stream>>>(res1, Wt, 1024);
      gemm256<<<256, 512, 0, stream>>>(xb, Wt, acc, (ushortT*)nullptr, 1024, HID, 16, 0);
    }

    // relation-batched feat GEMM: featb4[NTOT][4*4096] = Ab @ [W_0|W_1|W_2|W_3]
    for (int r = 0; r < RREL; r++)
      convt_k<<<convGrid, 256, 0, stream>>>(Wl + (size_t)r * K * HID,
                                            Wt + (size_t)r * HID * K, K);
    gemm256<<<1024, 512, 0, stream>>>(Ab, Wt, (float*)nullptr, featb4, K, NCOL, 64, 2);

    el_er_k<<<dim3(NTOT, RREL), 256, 0, stream>>>(featb4, all, arl, el, er);
    sm_k<<<dim3(NTOT * 4 / 256, RREL), 256, 0, stream>>>(src_pre, src_hyp, src_comb,
                                                         row_ptr, edge_ord, el, er, pbuf,
                                                         rinv);
    agg4_k<<<NTOT, 256, 0, stream>>>(featb4, pbuf, rinv, row_ptr, edge_ord, src_pre,
                                     src_hyp, src_comb, acc, layer == 0 ? 1 : 0);

    if (layer == 0) {
      finalize1_k<<<(size_t)NTOT * HID / 256, 256, 0, stream>>>(acc, b1, hb, NTOT * HID);
    } else {
      for (int g = 0; g < 3; g++) {
        dim3 fg(HID / 256, (gs[g].N + 31) / 32);
        finalize2_mean_k<<<fg, 256, 0, stream>>>(acc + (size_t)gs[g].goff * HID,
                                                 hb + (size_t)gs[g].goff * HID, b2,
                                                 gm + g * HID, gs[g].N, 1.0f / gs[g].N);
      }
    }
  }

  // readout MLP (fp32)
  initvec_k<<<12, 256, 0, stream>>>(z, bp, 3072);
  {
    dim3 mg(3072 / 256, 48);
    matvec_k<<<mg, 256, 0, stream>>>(gm, Wp, z, 12288, 3072, 256);
  }
  initvec_k<<<4, 256, 0, stream>>>(hc, bc1, 1024);
  {
    dim3 mg(1024 / 256, 24);
    matvec_k<<<mg, 256, 0, stream>>>(z, Wc1, hc, 3072, 1024, 128);
  }
  final_k<<<1, 256, 0, stream>>>(hc, Wc2, bc2, out);
}